// Round 8
// baseline (558.480 us; speedup 1.0000x reference)
//
#include <hip/hip_runtime.h>
#include <math.h>

#define B 4096
#define D 512
#define KC 4096
#define NIDX 131072
#define RR 3
#define TEMP 0.07f
#define M_II 14.5f   // |sim|/0.07 <= ~14.43 incl bf16 slop
#define M_IP 4.0f    // |sim|/density <= ~3.37 incl slop

// s_waitcnt immediates (gfx9 encoding: vm[3:0], exp[6:4], lgkm[11:8], vm_hi[15:14])
#define WC_VM4        0x0F74   // vmcnt(4), lgkm no-wait
#define WC_VM4_LGKM0  0x0074   // vmcnt(4), lgkm(0)  (inv_lds ds_write visibility)
#define WC_VM0        0x0F70   // vmcnt(0), lgkm no-wait

typedef __bf16 bf16x8 __attribute__((ext_vector_type(8)));
typedef float f32x4 __attribute__((ext_vector_type(4)));

__device__ __forceinline__ void gload_lds16(const void* g, void* l) {
  __builtin_amdgcn_global_load_lds(
      (const __attribute__((address_space(1))) unsigned int*)g,
      (__attribute__((address_space(3))) unsigned int*)l, 16, 0, 0);
}

__device__ __forceinline__ float dot8(float4 a0, float4 a1, float4 b0, float4 b1) {
  return a0.x * b0.x + a0.y * b0.y + a0.z * b0.z + a0.w * b0.w
       + a1.x * b1.x + a1.y * b1.y + a1.z * b1.z + a1.w * b1.w;
}

// ---------------- K1: fused prep: norm->bf16, proto gather->bf16, rho ----------------
__global__ __launch_bounds__(256) void prep_kernel(
    const float* __restrict__ audio, const float* __restrict__ frame,
    const float* __restrict__ a_cent, const float* __restrict__ a_dens,
    const float* __restrict__ f_cent, const float* __restrict__ f_dens,
    const int* __restrict__ vidx, const int* __restrict__ a_i2c,
    const int* __restrict__ f_i2c,
    __bf16* __restrict__ Xa, __bf16* __restrict__ Xf,
    __bf16* __restrict__ Yf, __bf16* __restrict__ Ya,
    float* __restrict__ invdd_f, float* __restrict__ invdd_a,
    float* __restrict__ rho) {
  const int u = blockIdx.x * 4 + (threadIdx.x >> 6);
  const int lane = threadIdx.x & 63;

  if (u < 8 * B) {
    const float* src; __bf16* dst;
    float* invArr = nullptr; const float* densp = nullptr;
    int slot = 0; size_t densIdx = 0;
    if (u < 2 * B) {
      if (u < B) { src = audio + (size_t)u * D; dst = Xa + (size_t)u * D; }
      else       { src = frame + (size_t)(u - B) * D; dst = Xf + (size_t)(u - B) * D; }
    } else {
      int q = u - 2 * B;
      int side = q / (RR * B);
      int rem = q - side * (RR * B);
      int r = rem / B;
      int j = rem - r * B;
      int idx = vidx[j];
      int pid;
      if (side == 0) {
        pid = f_i2c[r * NIDX + idx];
        src = f_cent + ((size_t)r * KC + pid) * D;
        dst = Yf + ((size_t)r * B + j) * D;
        invArr = invdd_f; densp = f_dens;
      } else {
        pid = a_i2c[r * NIDX + idx];
        src = a_cent + ((size_t)r * KC + pid) * D;
        dst = Ya + ((size_t)r * B + j) * D;
        invArr = invdd_a; densp = a_dens;
      }
      slot = r * B + j;
      densIdx = (size_t)r * KC + pid;
    }
    const float4* s4 = (const float4*)src + lane * 2;
    float4 v0 = s4[0], v1 = s4[1];
    float ss = dot8(v0, v1, v0, v1);
    #pragma unroll
    for (int off = 32; off >= 1; off >>= 1) ss += __shfl_xor(ss, off, 64);
    float invn = 1.f / fmaxf(sqrtf(ss), 1e-12f);
    __bf16 o[8];
    o[0] = (__bf16)(v0.x * invn); o[1] = (__bf16)(v0.y * invn);
    o[2] = (__bf16)(v0.z * invn); o[3] = (__bf16)(v0.w * invn);
    o[4] = (__bf16)(v1.x * invn); o[5] = (__bf16)(v1.y * invn);
    o[6] = (__bf16)(v1.z * invn); o[7] = (__bf16)(v1.w * invn);
    *(bf16x8*)(dst + lane * 8) = *(bf16x8*)o;
    if (invArr && lane == 0) invArr[slot] = 1.f / densp[densIdx];
  } else {
    const int i = u - 8 * B;
    const int idx = vidx[i];
    const float4* x4 = (const float4*)(audio + (size_t)i * D) + lane * 2;
    const float4* y4 = (const float4*)(frame + (size_t)i * D) + lane * 2;
    float4 a0 = x4[0], a1 = x4[1], f0 = y4[0], f1 = y4[1];
    float saf = dot8(a0, a1, f0, f1);
    float sa = dot8(a0, a1, a0, a1);
    float sf = dot8(f0, f1, f0, f1);
    float pc = 0.f;
    for (int r = 0; r < RR; ++r) {
      int ap = a_i2c[r * NIDX + idx];
      int fp = f_i2c[r * NIDX + idx];
      const float4* c4 = (const float4*)(a_cent + ((size_t)r * KC + ap) * D) + lane * 2;
      const float4* d4 = (const float4*)(f_cent + ((size_t)r * KC + fp) * D) + lane * 2;
      float4 c0 = c4[0], c1 = c4[1], e0 = d4[0], e1 = d4[1];
      pc += dot8(c0, c1, e0, e1);
    }
    #pragma unroll
    for (int off = 32; off >= 1; off >>= 1) {
      saf += __shfl_xor(saf, off, 64);
      sa  += __shfl_xor(sa, off, 64);
      sf  += __shfl_xor(sf, off, 64);
      pc  += __shfl_xor(pc, off, 64);
    }
    if (lane == 0)
      rho[i] = saf / (fmaxf(sqrtf(sa), 1e-12f) * fmaxf(sqrtf(sf), 1e-12f)) - pc;
  }
}

// ---------------- K2: fused bf16-MFMA GEMM + fixed-max LSE partials ----------------
// grid (32, 7, 4). BK=32 (proven best), K-loop software-pipelined:
// double-buffered LDS, raw s_barrier + s_waitcnt vmcnt(4) (never drain to 0 in
// steady state). Tile kt's glds are issued one full iteration ahead, so the
// former per-kt vmcnt(0) L2/L3 round-trip stall vanishes.
__global__ __launch_bounds__(256) void lse_mfma_kernel(
    const __bf16* __restrict__ Xa, const __bf16* __restrict__ Xf,
    const __bf16* __restrict__ Yf, const __bf16* __restrict__ Ya,
    const float* __restrict__ invdd_f, const float* __restrict__ invdd_a,
    float* __restrict__ sp, float* __restrict__ colsp,
    float* __restrict__ diagAll) {
  __shared__ __bf16 As[2 * 4096];      // [buf][row-chunked 8 KB], lane-linear
  __shared__ __bf16 Bs[2 * 4096];
  __shared__ float inv_lds[2][132];
  __shared__ float part_s[2 * 128];
  __shared__ float colpart[2][128];

  const int yy = blockIdx.y;
  const int job = (yy == 0) ? 0 : yy + 1;
  const int hf = blockIdx.z;
  const int i0 = blockIdx.x * 128;

  const __bf16* Ab; const __bf16* Bb; const float* invArr = nullptr;
  if (job == 0)      { Ab = Xa; Bb = Xf; }
  else if (job <= 4) { Ab = Xa; Bb = Yf + (size_t)(job - 2) * B * D;
                       invArr = invdd_f + (job - 2) * B; }
  else               { Ab = Xf; Bb = Ya + (size_t)(job - 5) * B * D;
                       invArr = invdd_a + (job - 5) * B; }
  const bool ii = (job == 0);
  const float invT = 1.f / TEMP;
  const float inv0 = ii ? invT : invArr[0];
  const float MJ = ii ? M_II : M_IP;

  const int tid = threadIdx.x;
  const int wv = tid >> 6;
  const int lane = tid & 63;
  const int wr = (wv >> 1) * 64;
  const int wc = (wv & 1) * 64;
  const int g = lane >> 4;
  const int cl = lane & 15;

  // staging: XOR-swizzled global source so LDS fragment reads are 2-way (free)
  const int srow = lane >> 2;
  const int skoff = (((lane & 3) ^ ((lane >> 3) & 3)) * 16);
  const int c0row = wv * 16 + srow;
  const int c1row = 64 + wv * 16 + srow;
  const char* gA0 = (const char*)Ab + (size_t)(i0 + c0row) * (D * 2) + skoff;
  const char* gA1 = (const char*)Ab + (size_t)(i0 + c1row) * (D * 2) + skoff;

  const int csw = (g ^ ((cl >> 1) & 3)) * 8;   // swizzled k-chunk for frag reads
  int aoff[4], boff[4];
  #pragma unroll
  for (int t = 0; t < 4; ++t) {
    aoff[t] = (wr + t * 16 + cl) * 32 + csw;
    boff[t] = (wc + t * 16 + cl) * 32 + csw;
  }

  float sacc[4][4];
  #pragma unroll
  for (int ri = 0; ri < 4; ++ri)
    #pragma unroll
    for (int v = 0; v < 4; ++v) sacc[ri][v] = 0.f;

  for (int jt = hf * 8; jt < hf * 8 + 8; ++jt) {
    const int j0 = jt * 128;
    float* invL = inv_lds[jt & 1];
    if (!ii && tid < 130) {
      int idx = j0 + tid; if (idx > B - 1) idx = B - 1;
      invL[tid] = invArr[idx];
    }
    const char* gB0 = (const char*)Bb + (size_t)(j0 + c0row) * (D * 2) + skoff;
    const char* gB1 = (const char*)Bb + (size_t)(j0 + c1row) * (D * 2) + skoff;

    f32x4 acc[4][4];
    #pragma unroll
    for (int ri = 0; ri < 4; ++ri)
      #pragma unroll
      for (int ci = 0; ci < 4; ++ci) acc[ri][ci] = (f32x4){0.f, 0.f, 0.f, 0.f};

    // ---- pipelined K-loop: prologue stages kt=0 into buf0 ----
    {
      gload_lds16(gA0, As + wv * 512);
      gload_lds16(gA1, As + 2048 + wv * 512);
      gload_lds16(gB0, Bs + wv * 512);
      gload_lds16(gB1, Bs + 2048 + wv * 512);
    }
    #pragma unroll
    for (int kt = 0; kt < 16; ++kt) {
      const int cur = kt & 1;
      if (kt < 15) {                      // stage kt+1 into the other buffer
        const int nb = (cur ^ 1) * 4096;
        const int kb = (kt + 1) * 64;
        gload_lds16(gA0 + kb, As + nb + wv * 512);
        gload_lds16(gA1 + kb, As + nb + 2048 + wv * 512);
        gload_lds16(gB0 + kb, Bs + nb + wv * 512);
        gload_lds16(gB1 + kb, Bs + nb + 2048 + wv * 512);
      }
      // wait only for CURRENT tile's 4 loads (issued last iteration); next
      // tile's 4 stay in flight across the barrier (AITER pattern).
      // NOTE: builtin requires a literal constant -> branch per unrolled kt.
      if (kt == 15)      __builtin_amdgcn_s_waitcnt(WC_VM0);
      else if (kt == 0)  __builtin_amdgcn_s_waitcnt(WC_VM4_LGKM0);
      else               __builtin_amdgcn_s_waitcnt(WC_VM4);
      __builtin_amdgcn_s_barrier();
      {
        const int cb = cur * 4096;
        bf16x8 af[4], bfr[4];
        #pragma unroll
        for (int t = 0; t < 4; ++t) {
          af[t] = *(const bf16x8*)(As + cb + aoff[t]);
          bfr[t] = *(const bf16x8*)(Bs + cb + boff[t]);
        }
        #pragma unroll
        for (int ri = 0; ri < 4; ++ri)
          #pragma unroll
          for (int ci = 0; ci < 4; ++ci)
            acc[ri][ci] = __builtin_amdgcn_mfma_f32_16x16x32_bf16(
                af[ri], bfr[ci], acc[ri][ci], 0, 0, 0);
      }
      // all waves done reading buf[cur] before next iteration overwrites it
      __builtin_amdgcn_s_barrier();
    }

    // epilogue: fixed-max accumulation (rows), plus column partials for job0
    float csum[4] = {0.f, 0.f, 0.f, 0.f};
    #pragma unroll
    for (int ri = 0; ri < 4; ++ri) {
      #pragma unroll
      for (int v = 0; v < 4; ++v) {
        const int gi = i0 + wr + ri * 16 + g * 4 + v;
        float acc4 = 0.f;
        #pragma unroll
        for (int ci = 0; ci < 4; ++ci) {
          const int jloc = wc + ci * 16 + cl;
          const int gj = j0 + jloc;
          float sc;
          if (ii) sc = invT;
          else    sc = (gj == gi) ? inv0 : invL[(gj < gi) ? (jloc + 1) : jloc];
          float lv = acc[ri][ci][v] * sc;
          if (gj == gi) diagAll[(size_t)job * B + gi] = lv;
          float ev = __expf(lv - MJ);
          acc4 += ev;
          if (ii) csum[ci] += ev;
        }
        sacc[ri][v] += acc4;
      }
    }
    if (ii) {
      #pragma unroll
      for (int ci = 0; ci < 4; ++ci) {
        csum[ci] += __shfl_xor(csum[ci], 16, 64);
        csum[ci] += __shfl_xor(csum[ci], 32, 64);
      }
      if (g == 0) {
        #pragma unroll
        for (int ci = 0; ci < 4; ++ci)
          colpart[wv >> 1][wc + ci * 16 + cl] = csum[ci];
      }
      __syncthreads();
      if (tid < 128)
        colsp[(size_t)blockIdx.x * B + j0 + tid] =
            colpart[0][tid] + colpart[1][tid];
    }
  }

  // single end-of-kernel reduction: 16 lanes (columns) -> LDS -> cross-wave pair
  #pragma unroll
  for (int ri = 0; ri < 4; ++ri) {
    #pragma unroll
    for (int v = 0; v < 4; ++v) {
      float s = sacc[ri][v];
      #pragma unroll
      for (int off = 8; off >= 1; off >>= 1) s += __shfl_xor(s, off, 64);
      if (cl == 0) part_s[(wv & 1) * 128 + wr + ri * 16 + g * 4 + v] = s;
    }
  }
  __syncthreads();
  if (tid < 128) {
    size_t o = ((size_t)job * 4 + hf) * B + i0 + tid;
    sp[o] = part_s[tid] + part_s[128 + tid];
  }
}

// ---------------- K3: fused LSE-merge (blocks 0..127) + stable rank (128..159) ----------------
__global__ __launch_bounds__(256) void merge_rank_kernel(
    const float* __restrict__ sp, const float* __restrict__ colsp,
    const float* __restrict__ diagAll, const float* __restrict__ rho,
    float* __restrict__ lossAll, int* __restrict__ rankArr,
    float* __restrict__ srho) {
  __shared__ float lr[B];
  __shared__ float cnt[256];
  const int blk = blockIdx.x;
  const int t = threadIdx.x;
  if (blk < 128) {
    int idx = blk * 256 + t;          // 0 .. 8*B-1
    int job = idx >> 12;
    int i = idx & (B - 1);
    if (job == 1) {
      float stot = 0.f;
      #pragma unroll 4
      for (int x = 0; x < 32; ++x) stot += colsp[(size_t)x * B + i];
      lossAll[idx] = M_II + logf(stot) - diagAll[i];
    } else {
      const float* s4 = sp + (size_t)job * 4 * B + i;
      float stot = s4[0] + s4[(size_t)B] + s4[(size_t)2 * B] + s4[(size_t)3 * B];
      float MJ = (job < 2) ? M_II : M_IP;
      lossAll[idx] = MJ + logf(stot) - diagAll[(size_t)job * B + i];
    }
  } else {
    const int base = (blk - 128) * 128;
    const int i = base + (t & 127);
    const int jlo = (t >> 7) * 2048;
    for (int k = t; k < B; k += 256) lr[k] = rho[k];
    __syncthreads();
    float my = lr[i];
    int rk = 0;
    for (int j = jlo; j < jlo + 2048; ++j) {
      float v = lr[j];
      rk += (v < my) || (v == my && j < i);   // stable: ties by index
    }
    cnt[t] = (float)rk;
    __syncthreads();
    if (t < 128) {
      int r = (int)cnt[t] + (int)cnt[t + 128];
      rankArr[i] = r;
      srho[r] = my;
    }
  }
}

// ---------------- K4: stats + gaussian pdf + cumsum + weights + final (one block) ----------------
__global__ __launch_bounds__(256) void cdf_final_kernel(
    const float* __restrict__ srho, const int* __restrict__ rankArr,
    const float* __restrict__ lossAll, float* __restrict__ out) {
  __shared__ float pdf[B];             // becomes yarr in place
  __shared__ float red[256];
  __shared__ float r1[256], r2[256];
  __shared__ float mv[2];
  const int t = threadIdx.x;
  float s = 0.f;
  for (int i = t; i < B; i += 256) s += srho[i];
  red[t] = s; __syncthreads();
  for (int off = 128; off >= 1; off >>= 1) {
    if (t < off) red[t] += red[t + off];
    __syncthreads();
  }
  float mean = red[0] / (float)B;
  __syncthreads();
  float v = 0.f;
  for (int i = t; i < B; i += 256) { float d = srho[i] - mean; v += d * d; }
  red[t] = v; __syncthreads();
  for (int off = 128; off >= 1; off >>= 1) {
    if (t < off) red[t] += red[t + off];
    __syncthreads();
  }
  if (t == 0) {
    float sd = sqrtf(red[0] / (float)B);
    mv[0] = mean + 0.3f * sd;          // mu = mean + DELTA*std
    mv[1] = sd * sqrtf(2.0f);          // sigma = std*sqrt(KA)
  }
  __syncthreads();
  float mu = mv[0], sg = mv[1];
  float c = 1.f / (2.5066282746310002f * sg);
  for (int k = t; k < B; k += 256) {
    float z = (srho[k] - mu) / sg;
    pdf[k] = expf(-0.5f * z * z) * c;
  }
  __syncthreads();
  const int base = t * (B / 256);
  float chunk = 0.f;
  for (int e = 0; e < B / 256; ++e) chunk += pdf[base + e];
  red[t] = chunk; __syncthreads();
  #pragma unroll
  for (int off = 1; off < 256; off <<= 1) {
    float add = (t >= off) ? red[t - off] : 0.f;
    __syncthreads();
    red[t] += add;
    __syncthreads();
  }
  float run = red[t] - chunk;          // exclusive base for this chunk
  for (int e = 0; e < B / 256; ++e) { run += pdf[base + e]; pdf[base + e] = run; }
  __syncthreads();
  const float ylast = pdf[B - 1];
  float sw = 0.f, s1 = 0.f, s2 = 0.f;
  for (int i = t; i < B; i += 256) {
    float wi = pdf[rankArr[i]] / ylast;
    float lpv = lossAll[2 * B + i] * (1.f / 27.f) + lossAll[3 * B + i] * (1.f / 9.f)
              + lossAll[4 * B + i] * (1.f / 3.f);
    float lpf = lossAll[5 * B + i] * (1.f / 27.f) + lossAll[6 * B + i] * (1.f / 9.f)
              + lossAll[7 * B + i] * (1.f / 3.f);
    sw += wi;
    s1 += wi * (lossAll[i] + lpv);
    s2 += wi * (lossAll[B + i] + lpf);
  }
  red[t] = sw; r1[t] = s1; r2[t] = s2; __syncthreads();
  for (int off = 128; off >= 1; off >>= 1) {
    if (t < off) { red[t] += red[t + off]; r1[t] += r1[t + off]; r2[t] += r2[t + off]; }
    __syncthreads();
  }
  if (t == 0) out[0] = r1[0] / red[0] + r2[0] / red[0];
}

extern "C" void kernel_launch(void* const* d_in, const int* in_sizes, int n_in,
                              void* d_out, int out_size, void* d_ws, size_t ws_size,
                              hipStream_t stream) {
  const float* audio  = (const float*)d_in[0];
  const float* frame  = (const float*)d_in[1];
  const float* a_cent = (const float*)d_in[2];
  const float* a_dens = (const float*)d_in[3];
  const float* f_cent = (const float*)d_in[4];
  const float* f_dens = (const float*)d_in[5];
  const int* vidx  = (const int*)d_in[6];
  const int* a_i2c = (const int*)d_in[7];
  const int* f_i2c = (const int*)d_in[8];
  float* out = (float*)d_out;

  const size_t BD = (size_t)B * D;
  char* base = (char*)d_ws;
  __bf16* Xa = (__bf16*)base;              base += BD * 2;
  __bf16* Xf = (__bf16*)base;              base += BD * 2;
  __bf16* Yf = (__bf16*)base;              base += 3 * BD * 2;
  __bf16* Ya = (__bf16*)base;              base += 3 * BD * 2;
  float* invdd_f = (float*)base;           base += 3 * B * 4;
  float* invdd_a = (float*)base;           base += 3 * B * 4;
  float* rho     = (float*)base;           base += B * 4;
  float* sp      = (float*)base;           base += 32 * B * 4;
  float* colsp   = (float*)base;           base += 32 * B * 4;
  float* diagAll = (float*)base;           base += 8 * B * 4;
  float* lossAll = (float*)base;           base += 8 * B * 4;
  float* srho    = (float*)base;           base += B * 4;
  int*   rankArr = (int*)base;

  prep_kernel<<<(9 * B) / 4, 256, 0, stream>>>(audio, frame, a_cent, a_dens,
                                               f_cent, f_dens, vidx, a_i2c, f_i2c,
                                               Xa, Xf, Yf, Ya, invdd_f, invdd_a, rho);

  dim3 g2(B / 128, 7, 4);
  lse_mfma_kernel<<<g2, 256, 0, stream>>>(Xa, Xf, Yf, Ya, invdd_f, invdd_a,
                                          sp, colsp, diagAll);

  merge_rank_kernel<<<160, 256, 0, stream>>>(sp, colsp, diagAll, rho,
                                             lossAll, rankArr, srho);
  cdf_final_kernel<<<1, 256, 0, stream>>>(srho, rankArr, lossAll, out);
}

// Round 9
// 484.510 us; speedup vs baseline: 1.1527x; 1.1527x over previous
//
#include <hip/hip_runtime.h>
#include <math.h>

#define B 4096
#define D 512
#define KC 4096
#define NIDX 131072
#define RR 3
#define TEMP 0.07f
#define M_II 14.5f   // |sim|/0.07 <= ~14.43 incl fp8 slop
#define M_IP 4.0f    // |sim|/density <= ~3.37 incl slop
#define DQ   0.00390625f   // 1/256: undo the 16x fp8 pre-scale on both operands

typedef float f32x4 __attribute__((ext_vector_type(4)));

__device__ __forceinline__ void gload_lds16(const void* g, void* l) {
  __builtin_amdgcn_global_load_lds(
      (const __attribute__((address_space(1))) unsigned int*)g,
      (__attribute__((address_space(3))) unsigned int*)l, 16, 0, 0);
}

__device__ __forceinline__ float dot8(float4 a0, float4 a1, float4 b0, float4 b1) {
  return a0.x * b0.x + a0.y * b0.y + a0.z * b0.z + a0.w * b0.w
       + a1.x * b1.x + a1.y * b1.y + a1.z * b1.z + a1.w * b1.w;
}

// float -> OCP e4m3fn, round-to-nearest-even, saturate at 448
__device__ __forceinline__ unsigned char f32_to_e4m3(float x) {
  unsigned int s = (__float_as_uint(x) >> 24) & 0x80u;
  float ax = fabsf(x);
  if (ax >= 448.f) return (unsigned char)(s | 0x7E);
  if (ax < 0.015625f) {                    // below min normal 2^-6: subnormals
    int m = (int)rintf(ax * 512.f);        // quantum 2^-9, RNE; 8 -> 0x08 = 2^-6
    return (unsigned char)(s | (unsigned)m);
  }
  unsigned int b = __float_as_uint(ax);
  b += 0x0007FFFFu + ((b >> 20) & 1u);     // RNE to 3 mantissa bits
  int e = (int)(b >> 23) - 127;            // re-extract (carry-safe)
  unsigned int m3 = (b >> 20) & 7u;
  return (unsigned char)(s | ((unsigned)(e + 7) << 3) | m3);
}

// ---------------- K1: fused prep: norm->fp8(x16), proto gather->fp8, rho ----------------
__global__ __launch_bounds__(256) void prep_kernel(
    const float* __restrict__ audio, const float* __restrict__ frame,
    const float* __restrict__ a_cent, const float* __restrict__ a_dens,
    const float* __restrict__ f_cent, const float* __restrict__ f_dens,
    const int* __restrict__ vidx, const int* __restrict__ a_i2c,
    const int* __restrict__ f_i2c,
    unsigned char* __restrict__ Xa, unsigned char* __restrict__ Xf,
    unsigned char* __restrict__ Yf, unsigned char* __restrict__ Ya,
    float* __restrict__ invdd_f, float* __restrict__ invdd_a,
    float* __restrict__ rho) {
  const int u = blockIdx.x * 4 + (threadIdx.x >> 6);
  const int lane = threadIdx.x & 63;

  if (u < 8 * B) {
    const float* src; unsigned char* dst;
    float* invArr = nullptr; const float* densp = nullptr;
    int slot = 0; size_t densIdx = 0;
    if (u < 2 * B) {
      if (u < B) { src = audio + (size_t)u * D; dst = Xa + (size_t)u * D; }
      else       { src = frame + (size_t)(u - B) * D; dst = Xf + (size_t)(u - B) * D; }
    } else {
      int q = u - 2 * B;
      int side = q / (RR * B);
      int rem = q - side * (RR * B);
      int r = rem / B;
      int j = rem - r * B;
      int idx = vidx[j];
      int pid;
      if (side == 0) {
        pid = f_i2c[r * NIDX + idx];
        src = f_cent + ((size_t)r * KC + pid) * D;
        dst = Yf + ((size_t)r * B + j) * D;
        invArr = invdd_f; densp = f_dens;
      } else {
        pid = a_i2c[r * NIDX + idx];
        src = a_cent + ((size_t)r * KC + pid) * D;
        dst = Ya + ((size_t)r * B + j) * D;
        invArr = invdd_a; densp = a_dens;
      }
      slot = r * B + j;
      densIdx = (size_t)r * KC + pid;
    }
    const float4* s4 = (const float4*)src + lane * 2;
    float4 v0 = s4[0], v1 = s4[1];
    float ss = dot8(v0, v1, v0, v1);
    #pragma unroll
    for (int off = 32; off >= 1; off >>= 1) ss += __shfl_xor(ss, off, 64);
    float q16 = 16.f / fmaxf(sqrtf(ss), 1e-12f);   // normalize and pre-scale x16
    unsigned char o[8];
    o[0] = f32_to_e4m3(v0.x * q16); o[1] = f32_to_e4m3(v0.y * q16);
    o[2] = f32_to_e4m3(v0.z * q16); o[3] = f32_to_e4m3(v0.w * q16);
    o[4] = f32_to_e4m3(v1.x * q16); o[5] = f32_to_e4m3(v1.y * q16);
    o[6] = f32_to_e4m3(v1.z * q16); o[7] = f32_to_e4m3(v1.w * q16);
    *(long*)(dst + lane * 8) = *(long*)o;
    if (invArr && lane == 0) invArr[slot] = 1.f / densp[densIdx];
  } else {
    const int i = u - 8 * B;
    const int idx = vidx[i];
    const float4* x4 = (const float4*)(audio + (size_t)i * D) + lane * 2;
    const float4* y4 = (const float4*)(frame + (size_t)i * D) + lane * 2;
    float4 a0 = x4[0], a1 = x4[1], f0 = y4[0], f1 = y4[1];
    float saf = dot8(a0, a1, f0, f1);
    float sa = dot8(a0, a1, a0, a1);
    float sf = dot8(f0, f1, f0, f1);
    float pc = 0.f;
    for (int r = 0; r < RR; ++r) {
      int ap = a_i2c[r * NIDX + idx];
      int fp = f_i2c[r * NIDX + idx];
      const float4* c4 = (const float4*)(a_cent + ((size_t)r * KC + ap) * D) + lane * 2;
      const float4* d4 = (const float4*)(f_cent + ((size_t)r * KC + fp) * D) + lane * 2;
      float4 c0 = c4[0], c1 = c4[1], e0 = d4[0], e1 = d4[1];
      pc += dot8(c0, c1, e0, e1);
    }
    #pragma unroll
    for (int off = 32; off >= 1; off >>= 1) {
      saf += __shfl_xor(saf, off, 64);
      sa  += __shfl_xor(sa, off, 64);
      sf  += __shfl_xor(sf, off, 64);
      pc  += __shfl_xor(pc, off, 64);
    }
    if (lane == 0)
      rho[i] = saf / (fmaxf(sqrtf(sa), 1e-12f) * fmaxf(sqrtf(sf), 1e-12f)) - pc;
  }
}

// ---------------- K2: fused fp8-MFMA GEMM + fixed-max LSE partials ----------------
// grid (32, 7, 8) = 1792 blocks = exactly 7/CU. BK=64 fp8 (64-byte LDS rows --
// identical staging geometry + 16B XOR swizzle as the proven bf16 r3 kernel,
// but 2x K per staged byte). r3 sync structure (single buffer, __syncthreads):
// every pipelining variant (r4/r6/r8) lost to occupancy; co-resident blocks
// cover the drains. job-slot 0 = ii (row-LSE v2f + col-LSE partials f2v);
// slots 1..6 = inst-proto jobs 2..7.
__global__ __launch_bounds__(256) void lse_mfma_kernel(
    const unsigned char* __restrict__ Xa, const unsigned char* __restrict__ Xf,
    const unsigned char* __restrict__ Yf, const unsigned char* __restrict__ Ya,
    const float* __restrict__ invdd_f, const float* __restrict__ invdd_a,
    float* __restrict__ sp, float* __restrict__ colsp,
    float* __restrict__ diagAll) {
  __shared__ unsigned char As[128 * 64];   // 8 KB: 128 rows x 64 k-bytes
  __shared__ unsigned char Bs[128 * 64];
  __shared__ float inv_lds[2][132];
  __shared__ float part_s[2 * 128];
  __shared__ float colpart[2][128];

  const int yy = blockIdx.y;
  const int job = (yy == 0) ? 0 : yy + 1;
  const int hf = blockIdx.z;
  const int i0 = blockIdx.x * 128;

  const unsigned char* Ab; const unsigned char* Bb; const float* invArr = nullptr;
  if (job == 0)      { Ab = Xa; Bb = Xf; }
  else if (job <= 4) { Ab = Xa; Bb = Yf + (size_t)(job - 2) * B * D;
                       invArr = invdd_f + (job - 2) * B; }
  else               { Ab = Xf; Bb = Ya + (size_t)(job - 5) * B * D;
                       invArr = invdd_a + (job - 5) * B; }
  const bool ii = (job == 0);
  const float invT = DQ / TEMP;                 // fold 1/256 dequant
  const float inv0 = ii ? invT : invArr[0] * DQ;
  const float MJ = ii ? M_II : M_IP;

  const int tid = threadIdx.x;
  const int wv = tid >> 6;
  const int lane = tid & 63;
  const int wr = (wv >> 1) * 64;
  const int wc = (wv & 1) * 64;
  const int g = lane >> 4;
  const int cl = lane & 15;

  // staging: XOR-swizzled global source (16B chunks), dest lane-linear (glds)
  const int srow = lane >> 2;
  const int skoff = (((lane & 3) ^ ((lane >> 3) & 3)) * 16);
  const int c0row = wv * 16 + srow;
  const int c1row = 64 + wv * 16 + srow;
  const unsigned char* gA0 = Ab + (size_t)(i0 + c0row) * D + skoff;
  const unsigned char* gA1 = Ab + (size_t)(i0 + c1row) * D + skoff;
  unsigned char* lA0 = As + wv * 1024;
  unsigned char* lA1 = As + 4096 + wv * 1024;
  unsigned char* lB0 = Bs + wv * 1024;
  unsigned char* lB1 = Bs + 4096 + wv * 1024;

  // fragment read offsets (h=0 k-half); h=1 is aoff ^ 32 (chunk bit1 flip)
  int aoff[4], boff[4];
  #pragma unroll
  for (int t = 0; t < 4; ++t) {
    const int ma = wr + t * 16 + cl;
    const int mb = wc + t * 16 + cl;
    aoff[t] = ma * 64 + (((g >> 1) ^ ((ma >> 1) & 3)) * 16) + (g & 1) * 8;
    boff[t] = mb * 64 + (((g >> 1) ^ ((mb >> 1) & 3)) * 16) + (g & 1) * 8;
  }

  float sacc[4][4];
  #pragma unroll
  for (int ri = 0; ri < 4; ++ri)
    #pragma unroll
    for (int v = 0; v < 4; ++v) sacc[ri][v] = 0.f;

  for (int jt = hf * 4; jt < hf * 4 + 4; ++jt) {
    const int j0 = jt * 128;
    float* invL = inv_lds[jt & 1];
    if (!ii && tid < 130) {
      int idx = j0 + tid; if (idx > B - 1) idx = B - 1;
      invL[tid] = invArr[idx] * DQ;            // fold dequant here
    }
    const unsigned char* gB0 = Bb + (size_t)(j0 + c0row) * D + skoff;
    const unsigned char* gB1 = Bb + (size_t)(j0 + c1row) * D + skoff;

    f32x4 acc[4][4];
    #pragma unroll
    for (int ri = 0; ri < 4; ++ri)
      #pragma unroll
      for (int ci = 0; ci < 4; ++ci) acc[ri][ci] = (f32x4){0.f, 0.f, 0.f, 0.f};

    for (int kt = 0; kt < 8; ++kt) {           // BK=64 fp8
      __syncthreads();
      const int kb = kt * 64;
      gload_lds16(gA0 + kb, lA0);
      gload_lds16(gA1 + kb, lA1);
      gload_lds16(gB0 + kb, lB0);
      gload_lds16(gB1 + kb, lB1);
      __syncthreads();
      #pragma unroll
      for (int h = 0; h < 2; ++h) {            // 2 x K=32 MFMA steps
        const int hx = h * 32;                 // XOR on chunk bit1
        long af[4], bfr[4];
        #pragma unroll
        for (int t = 0; t < 4; ++t) {
          af[t]  = *(const long*)(As + (aoff[t] ^ hx));
          bfr[t] = *(const long*)(Bs + (boff[t] ^ hx));
        }
        #pragma unroll
        for (int ri = 0; ri < 4; ++ri)
          #pragma unroll
          for (int ci = 0; ci < 4; ++ci)
            acc[ri][ci] = __builtin_amdgcn_mfma_f32_16x16x32_fp8_fp8(
                af[ri], bfr[ci], acc[ri][ci], 0, 0, 0);
      }
    }

    // epilogue: fixed-max accumulation (rows), plus column partials for job0
    float csum[4] = {0.f, 0.f, 0.f, 0.f};
    #pragma unroll
    for (int ri = 0; ri < 4; ++ri) {
      #pragma unroll
      for (int v = 0; v < 4; ++v) {
        const int gi = i0 + wr + ri * 16 + g * 4 + v;
        float acc4 = 0.f;
        #pragma unroll
        for (int ci = 0; ci < 4; ++ci) {
          const int jloc = wc + ci * 16 + cl;
          const int gj = j0 + jloc;
          float sc;
          if (ii) sc = invT;
          else    sc = (gj == gi) ? inv0 : invL[(gj < gi) ? (jloc + 1) : jloc];
          float lv = acc[ri][ci][v] * sc;
          if (gj == gi) diagAll[(size_t)job * B + gi] = lv;
          float ev = __expf(lv - MJ);
          acc4 += ev;
          if (ii) csum[ci] += ev;
        }
        sacc[ri][v] += acc4;
      }
    }
    if (ii) {
      #pragma unroll
      for (int ci = 0; ci < 4; ++ci) {
        csum[ci] += __shfl_xor(csum[ci], 16, 64);
        csum[ci] += __shfl_xor(csum[ci], 32, 64);
      }
      if (g == 0) {
        #pragma unroll
        for (int ci = 0; ci < 4; ++ci)
          colpart[wv >> 1][wc + ci * 16 + cl] = csum[ci];
      }
      __syncthreads();
      if (tid < 128)
        colsp[(size_t)blockIdx.x * B + j0 + tid] =
            colpart[0][tid] + colpart[1][tid];
    }
  }

  // end-of-kernel: 16 col-lanes -> LDS -> cross-wave pair
  #pragma unroll
  for (int ri = 0; ri < 4; ++ri) {
    #pragma unroll
    for (int v = 0; v < 4; ++v) {
      float s = sacc[ri][v];
      #pragma unroll
      for (int off = 8; off >= 1; off >>= 1) s += __shfl_xor(s, off, 64);
      if (cl == 0) part_s[(wv & 1) * 128 + wr + ri * 16 + g * 4 + v] = s;
    }
  }
  __syncthreads();
  if (tid < 128) {
    size_t o = ((size_t)job * 8 + hf) * B + i0 + tid;
    sp[o] = part_s[tid] + part_s[128 + tid];
  }
}

// ---------------- K3: fused LSE-merge (blocks 0..127) + stable rank (128..159) ----------------
__global__ __launch_bounds__(256) void merge_rank_kernel(
    const float* __restrict__ sp, const float* __restrict__ colsp,
    const float* __restrict__ diagAll, const float* __restrict__ rho,
    float* __restrict__ lossAll, int* __restrict__ rankArr,
    float* __restrict__ srho) {
  __shared__ float lr[B];
  __shared__ float cnt[256];
  const int blk = blockIdx.x;
  const int t = threadIdx.x;
  if (blk < 128) {
    int idx = blk * 256 + t;          // 0 .. 8*B-1
    int job = idx >> 12;
    int i = idx & (B - 1);
    if (job == 1) {
      float stot = 0.f;
      #pragma unroll 4
      for (int x = 0; x < 32; ++x) stot += colsp[(size_t)x * B + i];
      lossAll[idx] = M_II + logf(stot) - diagAll[i];
    } else {
      const float* s8 = sp + (size_t)job * 8 * B + i;
      float stot = 0.f;
      #pragma unroll
      for (int h = 0; h < 8; ++h) stot += s8[(size_t)h * B];
      float MJ = (job < 2) ? M_II : M_IP;
      lossAll[idx] = MJ + logf(stot) - diagAll[(size_t)job * B + i];
    }
  } else {
    const int base = (blk - 128) * 128;
    const int i = base + (t & 127);
    const int jlo = (t >> 7) * 2048;
    for (int k = t; k < B; k += 256) lr[k] = rho[k];
    __syncthreads();
    float my = lr[i];
    int rk = 0;
    for (int j = jlo; j < jlo + 2048; ++j) {
      float v = lr[j];
      rk += (v < my) || (v == my && j < i);   // stable: ties by index
    }
    cnt[t] = (float)rk;
    __syncthreads();
    if (t < 128) {
      int r = (int)cnt[t] + (int)cnt[t + 128];
      rankArr[i] = r;
      srho[r] = my;
    }
  }
}

// ---------------- K4: stats + gaussian pdf + cumsum + weights + final (one block) ----------------
__global__ __launch_bounds__(256) void cdf_final_kernel(
    const float* __restrict__ srho, const int* __restrict__ rankArr,
    const float* __restrict__ lossAll, float* __restrict__ out) {
  __shared__ float pdf[B];             // becomes yarr in place
  __shared__ float red[256];
  __shared__ float r1[256], r2[256];
  __shared__ float mv[2];
  const int t = threadIdx.x;
  float s = 0.f;
  for (int i = t; i < B; i += 256) s += srho[i];
  red[t] = s; __syncthreads();
  for (int off = 128; off >= 1; off >>= 1) {
    if (t < off) red[t] += red[t + off];
    __syncthreads();
  }
  float mean = red[0] / (float)B;
  __syncthreads();
  float v = 0.f;
  for (int i = t; i < B; i += 256) { float d = srho[i] - mean; v += d * d; }
  red[t] = v; __syncthreads();
  for (int off = 128; off >= 1; off >>= 1) {
    if (t < off) red[t] += red[t + off];
    __syncthreads();
  }
  if (t == 0) {
    float sd = sqrtf(red[0] / (float)B);
    mv[0] = mean + 0.3f * sd;          // mu = mean + DELTA*std
    mv[1] = sd * sqrtf(2.0f);          // sigma = std*sqrt(KA)
  }
  __syncthreads();
  float mu = mv[0], sg = mv[1];
  float c = 1.f / (2.5066282746310002f * sg);
  for (int k = t; k < B; k += 256) {
    float z = (srho[k] - mu) / sg;
    pdf[k] = expf(-0.5f * z * z) * c;
  }
  __syncthreads();
  const int base = t * (B / 256);
  float chunk = 0.f;
  for (int e = 0; e < B / 256; ++e) chunk += pdf[base + e];
  red[t] = chunk; __syncthreads();
  #pragma unroll
  for (int off = 1; off < 256; off <<= 1) {
    float add = (t >= off) ? red[t - off] : 0.f;
    __syncthreads();
    red[t] += add;
    __syncthreads();
  }
  float run = red[t] - chunk;          // exclusive base for this chunk
  for (int e = 0; e < B / 256; ++e) { run += pdf[base + e]; pdf[base + e] = run; }
  __syncthreads();
  const float ylast = pdf[B - 1];
  float sw = 0.f, s1 = 0.f, s2 = 0.f;
  for (int i = t; i < B; i += 256) {
    float wi = pdf[rankArr[i]] / ylast;
    float lpv = lossAll[2 * B + i] * (1.f / 27.f) + lossAll[3 * B + i] * (1.f / 9.f)
              + lossAll[4 * B + i] * (1.f / 3.f);
    float lpf = lossAll[5 * B + i] * (1.f / 27.f) + lossAll[6 * B + i] * (1.f / 9.f)
              + lossAll[7 * B + i] * (1.f / 3.f);
    sw += wi;
    s1 += wi * (lossAll[i] + lpv);
    s2 += wi * (lossAll[B + i] + lpf);
  }
  red[t] = sw; r1[t] = s1; r2[t] = s2; __syncthreads();
  for (int off = 128; off >= 1; off >>= 1) {
    if (t < off) { red[t] += red[t + off]; r1[t] += r1[t + off]; r2[t] += r2[t + off]; }
    __syncthreads();
  }
  if (t == 0) out[0] = r1[0] / red[0] + r2[0] / red[0];
}

extern "C" void kernel_launch(void* const* d_in, const int* in_sizes, int n_in,
                              void* d_out, int out_size, void* d_ws, size_t ws_size,
                              hipStream_t stream) {
  const float* audio  = (const float*)d_in[0];
  const float* frame  = (const float*)d_in[1];
  const float* a_cent = (const float*)d_in[2];
  const float* a_dens = (const float*)d_in[3];
  const float* f_cent = (const float*)d_in[4];
  const float* f_dens = (const float*)d_in[5];
  const int* vidx  = (const int*)d_in[6];
  const int* a_i2c = (const int*)d_in[7];
  const int* f_i2c = (const int*)d_in[8];
  float* out = (float*)d_out;

  const size_t BD = (size_t)B * D;
  char* base = (char*)d_ws;
  unsigned char* Xa = (unsigned char*)base; base += BD;
  unsigned char* Xf = (unsigned char*)base; base += BD;
  unsigned char* Yf = (unsigned char*)base; base += 3 * BD;
  unsigned char* Ya = (unsigned char*)base; base += 3 * BD;
  float* invdd_f = (float*)base;           base += 3 * B * 4;
  float* invdd_a = (float*)base;           base += 3 * B * 4;
  float* rho     = (float*)base;           base += B * 4;
  float* sp      = (float*)base;           base += 64 * B * 4;
  float* colsp   = (float*)base;           base += 32 * B * 4;
  float* diagAll = (float*)base;           base += 8 * B * 4;
  float* lossAll = (float*)base;           base += 8 * B * 4;
  float* srho    = (float*)base;           base += B * 4;
  int*   rankArr = (int*)base;

  prep_kernel<<<(9 * B) / 4, 256, 0, stream>>>(audio, frame, a_cent, a_dens,
                                               f_cent, f_dens, vidx, a_i2c, f_i2c,
                                               Xa, Xf, Yf, Ya, invdd_f, invdd_a, rho);

  dim3 g2(B / 128, 7, 8);
  lse_mfma_kernel<<<g2, 256, 0, stream>>>(Xa, Xf, Yf, Ya, invdd_f, invdd_a,
                                          sp, colsp, diagAll);

  merge_rank_kernel<<<160, 256, 0, stream>>>(sp, colsp, diagAll, rho,
                                             lossAll, rankArr, srho);
  cdf_final_kernel<<<1, 256, 0, stream>>>(srho, rankArr, lossAll, out);
}